// Round 14
// baseline (410.401 us; speedup 1.0000x reference)
//
#include <hip/hip_runtime.h>

// GCN forward, MI355X. v14 — atomic-free CSR build: chunk x range LDS
// histograms (k_hist) + in-place chunk prefix (k_merge2) + LDS-counter fill
// (k_fill2). v7/v8/v13 evidence: global atomics cost ~32B fabric RMW each
// (~22G/s floor, 71us for 1.6M); LDS atomics replace them entirely.
// Everything else identical to v13 (380us).

#define N_NODES 50000
#define N_EDGES 800000
#define D 128
#define NSH 8
#define PANEL ((size_t)N_NODES * 16)
#define NCHUNK 32
#define CSZ (N_EDGES / NCHUNK)     // 25000
#define NRANGE 16
#define RSZ (N_NODES / NRANGE)     // 3125

// ---------------- CSR build (no global atomics) ----------------

__global__ __launch_bounds__(256) void k_hist(const int* __restrict__ src, const int* __restrict__ dst,
                                              int* __restrict__ ghs, int* __restrict__ ghd) {
    __shared__ int hs[RSZ], hd[RSZ];
    const int c = blockIdx.x >> 4;          // chunk
    const int r = blockIdx.x & 15;          // range
    const int base = r * RSZ;
    const int t = threadIdx.x;
    for (int i = t; i < RSZ; i += 256) { hs[i] = 0; hd[i] = 0; }
    __syncthreads();
    const int e0 = c * CSZ, e1 = e0 + CSZ;
    for (int e = e0 + t; e < e1; e += 256) {
        unsigned dd = (unsigned)(dst[e] - base);
        if (dd < RSZ) atomicAdd(&hd[dd], 1);
        unsigned ss = (unsigned)(src[e] - base);
        if (ss < RSZ) atomicAdd(&hs[ss], 1);
    }
    __syncthreads();
    for (int i = t; i < RSZ; i += 256) {
        ghd[(size_t)c * N_NODES + base + i] = hd[i];
        ghs[(size_t)c * N_NODES + base + i] = hs[i];
    }
}

// per node: rowcnt = sum_c ghd; ghd[c][n] <- exclusive prefix (chunk base);
// dinv from summed src histogram.
__global__ __launch_bounds__(256) void k_merge2(int* __restrict__ ghd, const int* __restrict__ ghs,
                                                int* __restrict__ rowcnt, float* __restrict__ dinv, int n) {
    int i = blockIdx.x * 256 + threadIdx.x;
    if (i >= n) return;
    int run = 0;
#pragma unroll
    for (int c = 0; c < NCHUNK; c++) {
        int v = ghd[(size_t)c * N_NODES + i];
        ghd[(size_t)c * N_NODES + i] = run;
        run += v;
    }
    rowcnt[i] = run;
    int ds = 0;
#pragma unroll
    for (int c = 0; c < NCHUNK; c++) ds += ghs[(size_t)c * N_NODES + i];
    dinv[i] = 1.0f / (float)(ds > 1 ? ds : 1);
}

__global__ __launch_bounds__(1024) void k_scan1(const int* __restrict__ cnt, int* __restrict__ excl,
                                                int* __restrict__ blocksum, int n) {
    __shared__ int wsum[16];
    int i = blockIdx.x * 1024 + threadIdx.x;
    int v = (i < n) ? cnt[i] : 0;
    int lane = threadIdx.x & 63, wid = threadIdx.x >> 6;
    int x = v;
#pragma unroll
    for (int off = 1; off < 64; off <<= 1) {
        int y = __shfl_up(x, off, 64);
        if (lane >= off) x += y;
    }
    if (lane == 63) wsum[wid] = x;
    __syncthreads();
    if (threadIdx.x == 0) {
        int run = 0;
        for (int w = 0; w < 16; w++) { int t = wsum[w]; wsum[w] = run; run += t; }
        blocksum[blockIdx.x] = run;
    }
    __syncthreads();
    if (i < n) excl[i] = (x - v) + wsum[wid];
}

__global__ void k_scan2(const int* __restrict__ blocksum, int* __restrict__ blockoff,
                        int* __restrict__ rowptr_last, int nblk) {
    if (threadIdx.x == 0) {
        int run = 0;
        for (int b = 0; b < nblk; b++) { int t = blocksum[b]; blockoff[b] = run; run += t; }
        rowptr_last[0] = run;
    }
}

__global__ __launch_bounds__(1024) void k_scan3(int* __restrict__ excl, const int* __restrict__ blockoff, int n) {
    int i = blockIdx.x * 1024 + threadIdx.x;
    if (i < n) excl[i] += blockoff[blockIdx.x];
}

// fill: position from LDS counter; rowptr + chunk-base staged in LDS.
__global__ __launch_bounds__(256) void k_fill2(const int* __restrict__ src, const int* __restrict__ dst,
                                               const int* __restrict__ rowptr, const int* __restrict__ ghd,
                                               int* __restrict__ csrc) {
    __shared__ int cnt[RSZ];
    __shared__ int rpl[RSZ];
    __shared__ int gbl[RSZ];
    const int c = blockIdx.x >> 4;
    const int r = blockIdx.x & 15;
    const int base = r * RSZ;
    const int t = threadIdx.x;
    for (int i = t; i < RSZ; i += 256) {
        cnt[i] = 0;
        rpl[i] = rowptr[base + i];
        gbl[i] = ghd[(size_t)c * N_NODES + base + i];
    }
    __syncthreads();
    const int e0 = c * CSZ, e1 = e0 + CSZ;
    for (int e = e0 + t; e < e1; e += 256) {
        int d = dst[e];
        unsigned dd = (unsigned)(d - base);
        if (dd < RSZ) {
            int p = atomicAdd(&cnt[dd], 1);
            csrc[rpl[dd] + gbl[dd] + p] = src[e];
        }
    }
}

// ---------------- panelize: outp[p][node][16] = features[node][p*16..] * dinv[node] ----------------

__global__ __launch_bounds__(256) void k_panelize(const float* __restrict__ in, const float* __restrict__ dinv,
                                                  float* __restrict__ outp) {
    int tid = blockIdx.x * 256 + threadIdx.x;          // N_NODES*32 threads
    if (tid >= N_NODES * 32) return;
    int p = tid / (N_NODES * 4);
    int r = tid - p * (N_NODES * 4);
    int node = r >> 2, qq = r & 3;
    float w = dinv[node];
    float4 v = *reinterpret_cast<const float4*>(&in[(size_t)node * D + p * 16 + qq * 4]);
    v.x *= w; v.y *= w; v.z *= w; v.w *= w;
    *reinterpret_cast<float4*>(&outp[(size_t)p * PANEL + (size_t)node * 16 + qq * 4]) = v;
}

// ---------------- SpMM aggregation: panels, static XCD slices, float4 lanes ----------------

__global__ __launch_bounds__(256) void k_agg(const float* __restrict__ hp,
                                             const int* __restrict__ rp, const int* __restrict__ csrc,
                                             float* __restrict__ outp) {
    const int l4 = threadIdx.x & 3;
    const int grp = threadIdx.x >> 2;               // 0..63
    const int slice = blockIdx.x & (NSH - 1);
    const int node = (blockIdx.x >> 3) * 64 + grp;
    if (node >= N_NODES) return;
    const float* __restrict__ pan = hp + (size_t)slice * PANEL + l4 * 4;
    int s0 = rp[node], s1 = rp[node + 1];
    float4 acc = {0.f, 0.f, 0.f, 0.f};
    int e = s0;
    int npre = (s0 + 3) & ~3; if (npre > s1) npre = s1;
    for (; e < npre; e++) {                          // align to int4
        float4 a = *reinterpret_cast<const float4*>(&pan[(size_t)csrc[e] * 16]);
        acc.x += a.x; acc.y += a.y; acc.z += a.z; acc.w += a.w;
    }
    for (; e + 4 <= s1; e += 4) {
        int4 ii = *reinterpret_cast<const int4*>(&csrc[e]);
        float4 a = *reinterpret_cast<const float4*>(&pan[(size_t)ii.x * 16]);
        float4 b = *reinterpret_cast<const float4*>(&pan[(size_t)ii.y * 16]);
        float4 c = *reinterpret_cast<const float4*>(&pan[(size_t)ii.z * 16]);
        float4 d = *reinterpret_cast<const float4*>(&pan[(size_t)ii.w * 16]);
        acc.x += (a.x + b.x) + (c.x + d.x);
        acc.y += (a.y + b.y) + (c.y + d.y);
        acc.z += (a.z + b.z) + (c.z + d.z);
        acc.w += (a.w + b.w) + (c.w + d.w);
    }
    for (; e < s1; e++) {
        float4 a = *reinterpret_cast<const float4*>(&pan[(size_t)csrc[e] * 16]);
        acc.x += a.x; acc.y += a.y; acc.z += a.z; acc.w += a.w;
    }
    *reinterpret_cast<float4*>(&outp[(size_t)slice * PANEL + (size_t)node * 16 + l4 * 4]) = acc;
}

// ---------------- dense layer, panel I/O (+ fused epilogues) ----------------

__global__ __launch_bounds__(256) void k_gemm(const float* __restrict__ in, const float* __restrict__ W,
                                              const float* __restrict__ bias, float* __restrict__ out,
                                              int nrows, int relu,
                                              const float* __restrict__ dscale,
                                              const float* __restrict__ pw, const float* __restrict__ pb,
                                              float* __restrict__ pi_out, float* __restrict__ colsum) {
    __shared__ float wl[D * D];      // 64 KB
    __shared__ float at[D * 32];     // 16 KB (80 KB total: 2 blocks/CU)
    int t = threadIdx.x;
    const int head = (pw != nullptr);
    for (int i = t; i < D * D / 4; i += 256)
        reinterpret_cast<float4*>(wl)[i] = reinterpret_cast<const float4*>(W)[i];
    const int tx = t & 31;
    const int ty = t >> 5;
    const int ldrow = t & 31;
    const int ldc   = t >> 5;        // = panel index for staging
    float4 bv = reinterpret_cast<const float4*>(bias)[tx];
    float4 pwv = head ? reinterpret_cast<const float4*>(pw)[tx] : float4{0.f, 0.f, 0.f, 0.f};
    float pb0 = head ? pb[0] : 0.f;
    const int op = tx >> 2, oq = tx & 3;   // output panel / offset
    float cs0 = 0.f, cs1 = 0.f, cs2 = 0.f, cs3 = 0.f;
    int ntiles = (nrows + 31) / 32;

    for (int tile = blockIdx.x; tile < ntiles; tile += gridDim.x) {
        int row0 = tile * 32;
        __syncthreads();
        {
            int gr = row0 + ldrow;
            float va[16];
            if (gr < nrows) {
                const float4* ap = reinterpret_cast<const float4*>(&in[(size_t)ldc * PANEL + (size_t)gr * 16]);
#pragma unroll
                for (int qq = 0; qq < 4; qq++) {
                    float4 v = ap[qq];
                    va[qq * 4 + 0] = v.x; va[qq * 4 + 1] = v.y;
                    va[qq * 4 + 2] = v.z; va[qq * 4 + 3] = v.w;
                }
            } else {
#pragma unroll
                for (int qq = 0; qq < 16; qq++) va[qq] = 0.f;
            }
            int kb = ldc * 16;
#pragma unroll
            for (int j = 0; j < 16; j++) at[(kb + j) * 32 + ldrow] = va[j];
        }
        __syncthreads();

        float acc[4][4];
#pragma unroll
        for (int j = 0; j < 4; j++)
#pragma unroll
            for (int c = 0; c < 4; c++) acc[j][c] = 0.f;

#pragma unroll 8
        for (int k = 0; k < D; k++) {
            float4 a = *reinterpret_cast<const float4*>(&at[k * 32 + ty * 4]);
            float4 w = *reinterpret_cast<const float4*>(&wl[k * D + tx * 4]);
            acc[0][0] += a.x * w.x; acc[0][1] += a.x * w.y; acc[0][2] += a.x * w.z; acc[0][3] += a.x * w.w;
            acc[1][0] += a.y * w.x; acc[1][1] += a.y * w.y; acc[1][2] += a.y * w.z; acc[1][3] += a.y * w.w;
            acc[2][0] += a.z * w.x; acc[2][1] += a.z * w.y; acc[2][2] += a.z * w.z; acc[2][3] += a.z * w.w;
            acc[3][0] += a.w * w.x; acc[3][1] += a.w * w.y; acc[3][2] += a.w * w.z; acc[3][3] += a.w * w.w;
        }

#pragma unroll
        for (int j = 0; j < 4; j++) {
            int gr = row0 + ty * 4 + j;
            if (gr < nrows) {
                float4 o;
                o.x = acc[j][0] + bv.x; o.y = acc[j][1] + bv.y;
                o.z = acc[j][2] + bv.z; o.w = acc[j][3] + bv.w;
                if (relu) {
                    o.x = fmaxf(o.x, 0.f); o.y = fmaxf(o.y, 0.f);
                    o.z = fmaxf(o.z, 0.f); o.w = fmaxf(o.w, 0.f);
                }
                if (head) {
                    cs0 += o.x; cs1 += o.y; cs2 += o.z; cs3 += o.w;
                    float pr = o.x * pwv.x + o.y * pwv.y + o.z * pwv.z + o.w * pwv.w;
#pragma unroll
                    for (int off = 16; off > 0; off >>= 1) pr += __shfl_xor(pr, off, 32);
                    if (tx == 0) pi_out[gr] = pr + pb0;
                } else {
                    if (dscale) {
                        float w = dscale[gr];
                        o.x *= w; o.y *= w; o.z *= w; o.w *= w;
                    }
                    *reinterpret_cast<float4*>(&out[(size_t)op * PANEL + (size_t)gr * 16 + oq * 4]) = o;
                }
            }
        }
    }

    if (head) {
        __syncthreads();
        float* csl = at;
        if (t < D) csl[t] = 0.f;
        __syncthreads();
        atomicAdd(&csl[tx * 4 + 0], cs0);
        atomicAdd(&csl[tx * 4 + 1], cs1);
        atomicAdd(&csl[tx * 4 + 2], cs2);
        atomicAdd(&csl[tx * 4 + 3], cs3);
        __syncthreads();
        if (t < D) atomicAdd(&colsum[t], csl[t]);
    }
}

// ---------------- value head ----------------

__global__ __launch_bounds__(128) void k_value(const float* __restrict__ colsum, const float* __restrict__ vw,
                                               const float* __restrict__ vb, float* __restrict__ out) {
    __shared__ float red[128];
    int t = threadIdx.x;
    red[t] = (colsum[t] * (1.0f / (float)N_NODES)) * vw[t];
    __syncthreads();
    for (int s = 64; s > 0; s >>= 1) {
        if (t < s) red[t] += red[t + s];
        __syncthreads();
    }
    if (t == 0) out[0] = red[0] + vb[0];
}

__global__ __launch_bounds__(64) void k_ws_too_small(float* __restrict__ out, int n) {
    int i = blockIdx.x * 64 + threadIdx.x;
    if (i < n) out[i] = -1e30f;
}

// ---------------- launch ----------------

extern "C" void kernel_launch(void* const* d_in, const int* in_sizes, int n_in,
                              void* d_out, int out_size, void* d_ws, size_t ws_size,
                              hipStream_t stream) {
    const float* features = (const float*)d_in[0];
    const int*   src      = (const int*)d_in[1];
    const int*   dst      = (const int*)d_in[2];
    const float* W1 = (const float*)d_in[3];
    const float* b1 = (const float*)d_in[4];
    const float* W2 = (const float*)d_in[5];
    const float* b2 = (const float*)d_in[6];
    const float* W3 = (const float*)d_in[7];
    const float* b3 = (const float*)d_in[8];
    const float* pw = (const float*)d_in[9];
    const float* pb = (const float*)d_in[10];
    const float* vw = (const float*)d_in[11];
    const float* vb = (const float*)d_in[12];
    float* out = (float*)d_out;

    char* ws = (char*)d_ws;
    size_t off = 0;
    auto alloc = [&](size_t bytes) -> char* {
        char* p = ws + off;
        off += (bytes + 255) & ~(size_t)255;
        return p;
    };
    float* dinv     = (float*)alloc((size_t)N_NODES * 4);
    int*   rowptr   = (int*)alloc((size_t)(N_NODES + 1) * 4);
    int*   blocksum = (int*)alloc(64 * 4);
    int*   blockoff = (int*)alloc(64 * 4);
    float* colsum   = (float*)alloc(D * 4);
    int*   csrc     = (int*)alloc((size_t)N_EDGES * 4);
    float* bufA     = (float*)alloc((size_t)N_NODES * D * 4);
    float* bufB     = (float*)alloc((size_t)N_NODES * D * 4);

    // CSR-build temporaries overlay bufB (dead once agg-1 writes bufB):
    // [ghd: 32N][ghs: 32N][rowcnt: N] ints = 13 MB < 25.6 MB.
    int* ghd    = (int*)bufB;
    int* ghs    = ghd + (size_t)NCHUNK * N_NODES;
    int* rowcnt = ghs + (size_t)NCHUNK * N_NODES;

    if (off > ws_size) {
        k_ws_too_small<<<(out_size + 63) / 64, 64, 0, stream>>>(out, out_size);
        return;
    }

    hipMemsetAsync(colsum, 0, (size_t)D * 4, stream);

    // CSR build: zero global atomics.
    k_hist<<<NCHUNK * NRANGE, 256, 0, stream>>>(src, dst, ghs, ghd);
    k_merge2<<<(N_NODES + 255) / 256, 256, 0, stream>>>(ghd, ghs, rowcnt, dinv, N_NODES);

    int nblk = (N_NODES + 1023) / 1024;
    k_scan1<<<nblk, 1024, 0, stream>>>(rowcnt, rowptr, blocksum, N_NODES);
    k_scan2<<<1, 64, 0, stream>>>(blocksum, blockoff, rowptr + N_NODES, nblk);
    k_scan3<<<nblk, 1024, 0, stream>>>(rowptr, blockoff, N_NODES);
    k_fill2<<<NCHUNK * NRANGE, 256, 0, stream>>>(src, dst, rowptr, ghd, csrc);

    // panelize features*dinv -> bufA (panels)
    k_panelize<<<(N_NODES * 32 + 255) / 256, 256, 0, stream>>>(features, dinv, bufA);

    int aggblocks = ((N_NODES + 63) / 64) * NSH;    // 782*8 = 6256
    // layer 1: agg(bufA)->bufB ; gemm in-place panels (+dinv scale for next layer)
    k_agg<<<aggblocks, 256, 0, stream>>>(bufA, rowptr, csrc, bufB);
    k_gemm<<<512, 256, 0, stream>>>(bufB, W1, b1, bufB, N_NODES, 1, dinv,
                                    nullptr, nullptr, nullptr, nullptr);
    // layer 2
    k_agg<<<aggblocks, 256, 0, stream>>>(bufB, rowptr, csrc, bufA);
    k_gemm<<<512, 256, 0, stream>>>(bufA, W2, b2, bufA, N_NODES, 1, dinv,
                                    nullptr, nullptr, nullptr, nullptr);
    // layer 3: head mode (PI -> out, colsum; h3 never stored)
    k_agg<<<aggblocks, 256, 0, stream>>>(bufA, rowptr, csrc, bufB);
    k_gemm<<<512, 256, 0, stream>>>(bufB, W3, b3, nullptr, N_NODES, 0, nullptr,
                                    pw, pb, out, colsum);

    k_value<<<1, 128, 0, stream>>>(colsum, vw, vb, out + N_NODES);
}

// Round 15
// 341.735 us; speedup vs baseline: 1.2009x; 1.2009x over previous
//
#include <hip/hip_runtime.h>

// GCN forward, MI355X. v15 — CSR build via full-range packed-u16 LDS
// histograms: 2 counters/u32 word -> 50000 nodes in 100KB LDS, so each
// chunk is streamed ONCE (v14 streamed 16x at 19% occupancy). 64 chunks x
// {dst,src} = 128 blocks; zero global atomics. Rest identical to v13 (380us).

#define N_NODES 50000
#define N_EDGES 800000
#define D 128
#define NSH 8
#define PANEL ((size_t)N_NODES * 16)
#define NC 64
#define CSZ (N_EDGES / NC)          // 12500
#define NW (N_NODES / 2)            // 25000 packed words

// ---------------- CSR build (no global atomics) ----------------
// hist: block b -> array (b&1: 0=dst,1=src), chunk (b>>1). Full-range packed
// histogram in LDS; partial out[chunk][word] = packed counts.

__global__ __launch_bounds__(512) void k_hist3(const int* __restrict__ src, const int* __restrict__ dst,
                                               unsigned* __restrict__ ghd16, unsigned* __restrict__ ghs16) {
    __shared__ unsigned h[NW];          // 100 KB
    const int arr = blockIdx.x & 1;
    const int c   = blockIdx.x >> 1;
    const int t = threadIdx.x;
    for (int i = t; i < NW; i += 512) h[i] = 0u;
    __syncthreads();
    const int* __restrict__ col = arr ? src : dst;
    const int e0 = c * CSZ, e1 = e0 + CSZ;
    for (int e = e0 + t; e < e1; e += 512) {
        int n = col[e];
        atomicAdd(&h[n >> 1], 1u << ((n & 1) << 4));
    }
    __syncthreads();
    unsigned* __restrict__ outp = (arr ? ghs16 : ghd16) + (size_t)c * NW;
    for (int i = t; i < NW; i += 512) outp[i] = h[i];
}

// merge: per word — dst partials -> exclusive chunk prefix (in place, packed)
// + rowcnt; src partials -> dinv.
__global__ __launch_bounds__(256) void k_merge3(unsigned* __restrict__ ghd16, const unsigned* __restrict__ ghs16,
                                                int* __restrict__ rowcnt, float* __restrict__ dinv) {
    int w = blockIdx.x * 256 + threadIdx.x;
    if (w >= NW) return;
    unsigned runlo = 0, runhi = 0;
#pragma unroll
    for (int c = 0; c < NC; c++) {
        unsigned v = ghd16[(size_t)c * NW + w];
        ghd16[(size_t)c * NW + w] = runlo | (runhi << 16);
        runlo += v & 0xffffu; runhi += v >> 16;
    }
    rowcnt[2 * w] = (int)runlo;
    rowcnt[2 * w + 1] = (int)runhi;
    unsigned dlo = 0, dhi = 0;
#pragma unroll
    for (int c = 0; c < NC; c++) {
        unsigned v = ghs16[(size_t)c * NW + w];
        dlo += v & 0xffffu; dhi += v >> 16;
    }
    dinv[2 * w]     = 1.0f / (float)(dlo > 1u ? dlo : 1u);
    dinv[2 * w + 1] = 1.0f / (float)(dhi > 1u ? dhi : 1u);
}

__global__ __launch_bounds__(1024) void k_scan1(const int* __restrict__ cnt, int* __restrict__ excl,
                                                int* __restrict__ blocksum, int n) {
    __shared__ int wsum[16];
    int i = blockIdx.x * 1024 + threadIdx.x;
    int v = (i < n) ? cnt[i] : 0;
    int lane = threadIdx.x & 63, wid = threadIdx.x >> 6;
    int x = v;
#pragma unroll
    for (int off = 1; off < 64; off <<= 1) {
        int y = __shfl_up(x, off, 64);
        if (lane >= off) x += y;
    }
    if (lane == 63) wsum[wid] = x;
    __syncthreads();
    if (threadIdx.x == 0) {
        int run = 0;
        for (int w = 0; w < 16; w++) { int t = wsum[w]; wsum[w] = run; run += t; }
        blocksum[blockIdx.x] = run;
    }
    __syncthreads();
    if (i < n) excl[i] = (x - v) + wsum[wid];
}

__global__ void k_scan2(const int* __restrict__ blocksum, int* __restrict__ blockoff,
                        int* __restrict__ rowptr_last, int nblk) {
    if (threadIdx.x == 0) {
        int run = 0;
        for (int b = 0; b < nblk; b++) { int t = blocksum[b]; blockoff[b] = run; run += t; }
        rowptr_last[0] = run;
    }
}

__global__ __launch_bounds__(1024) void k_scan3(int* __restrict__ excl, const int* __restrict__ blockoff, int n) {
    int i = blockIdx.x * 1024 + threadIdx.x;
    if (i < n) excl[i] += blockoff[blockIdx.x];
}

// fill: block per chunk; packed LDS counters give within-(chunk,node) pos;
// slot = rowptr[d] + base[c][d] + p. Plain store, no global atomics.
__global__ __launch_bounds__(512) void k_fill3(const int* __restrict__ src, const int* __restrict__ dst,
                                               const int* __restrict__ rowptr, const unsigned* __restrict__ ghd16,
                                               int* __restrict__ csrc) {
    __shared__ unsigned cnt[NW];        // 100 KB
    const int c = blockIdx.x;
    const int t = threadIdx.x;
    for (int i = t; i < NW; i += 512) cnt[i] = 0u;
    __syncthreads();
    const unsigned* __restrict__ basep = ghd16 + (size_t)c * NW;
    const int e0 = c * CSZ, e1 = e0 + CSZ;
    for (int e = e0 + t; e < e1; e += 512) {
        int d = dst[e];
        int sh = (d & 1) << 4;
        unsigned old = atomicAdd(&cnt[d >> 1], 1u << sh);
        int p = (int)((old >> sh) & 0xffffu);
        int base = (int)((basep[d >> 1] >> sh) & 0xffffu);
        csrc[rowptr[d] + base + p] = src[e];
    }
}

// ---------------- panelize: outp[p][node][16] = features[node][p*16..] * dinv[node] ----------------

__global__ __launch_bounds__(256) void k_panelize(const float* __restrict__ in, const float* __restrict__ dinv,
                                                  float* __restrict__ outp) {
    int tid = blockIdx.x * 256 + threadIdx.x;          // N_NODES*32 threads
    if (tid >= N_NODES * 32) return;
    int p = tid / (N_NODES * 4);
    int r = tid - p * (N_NODES * 4);
    int node = r >> 2, qq = r & 3;
    float w = dinv[node];
    float4 v = *reinterpret_cast<const float4*>(&in[(size_t)node * D + p * 16 + qq * 4]);
    v.x *= w; v.y *= w; v.z *= w; v.w *= w;
    *reinterpret_cast<float4*>(&outp[(size_t)p * PANEL + (size_t)node * 16 + qq * 4]) = v;
}

// ---------------- SpMM aggregation: panels, static XCD slices, float4 lanes ----------------

__global__ __launch_bounds__(256) void k_agg(const float* __restrict__ hp,
                                             const int* __restrict__ rp, const int* __restrict__ csrc,
                                             float* __restrict__ outp) {
    const int l4 = threadIdx.x & 3;
    const int grp = threadIdx.x >> 2;               // 0..63
    const int slice = blockIdx.x & (NSH - 1);
    const int node = (blockIdx.x >> 3) * 64 + grp;
    if (node >= N_NODES) return;
    const float* __restrict__ pan = hp + (size_t)slice * PANEL + l4 * 4;
    int s0 = rp[node], s1 = rp[node + 1];
    float4 acc = {0.f, 0.f, 0.f, 0.f};
    int e = s0;
    int npre = (s0 + 3) & ~3; if (npre > s1) npre = s1;
    for (; e < npre; e++) {                          // align to int4
        float4 a = *reinterpret_cast<const float4*>(&pan[(size_t)csrc[e] * 16]);
        acc.x += a.x; acc.y += a.y; acc.z += a.z; acc.w += a.w;
    }
    for (; e + 4 <= s1; e += 4) {
        int4 ii = *reinterpret_cast<const int4*>(&csrc[e]);
        float4 a = *reinterpret_cast<const float4*>(&pan[(size_t)ii.x * 16]);
        float4 b = *reinterpret_cast<const float4*>(&pan[(size_t)ii.y * 16]);
        float4 c = *reinterpret_cast<const float4*>(&pan[(size_t)ii.z * 16]);
        float4 d = *reinterpret_cast<const float4*>(&pan[(size_t)ii.w * 16]);
        acc.x += (a.x + b.x) + (c.x + d.x);
        acc.y += (a.y + b.y) + (c.y + d.y);
        acc.z += (a.z + b.z) + (c.z + d.z);
        acc.w += (a.w + b.w) + (c.w + d.w);
    }
    for (; e < s1; e++) {
        float4 a = *reinterpret_cast<const float4*>(&pan[(size_t)csrc[e] * 16]);
        acc.x += a.x; acc.y += a.y; acc.z += a.z; acc.w += a.w;
    }
    *reinterpret_cast<float4*>(&outp[(size_t)slice * PANEL + (size_t)node * 16 + l4 * 4]) = acc;
}

// ---------------- dense layer, panel I/O (+ fused epilogues) ----------------

__global__ __launch_bounds__(256) void k_gemm(const float* __restrict__ in, const float* __restrict__ W,
                                              const float* __restrict__ bias, float* __restrict__ out,
                                              int nrows, int relu,
                                              const float* __restrict__ dscale,
                                              const float* __restrict__ pw, const float* __restrict__ pb,
                                              float* __restrict__ pi_out, float* __restrict__ colsum) {
    __shared__ float wl[D * D];      // 64 KB
    __shared__ float at[D * 32];     // 16 KB (80 KB total: 2 blocks/CU)
    int t = threadIdx.x;
    const int head = (pw != nullptr);
    for (int i = t; i < D * D / 4; i += 256)
        reinterpret_cast<float4*>(wl)[i] = reinterpret_cast<const float4*>(W)[i];
    const int tx = t & 31;
    const int ty = t >> 5;
    const int ldrow = t & 31;
    const int ldc   = t >> 5;        // = panel index for staging
    float4 bv = reinterpret_cast<const float4*>(bias)[tx];
    float4 pwv = head ? reinterpret_cast<const float4*>(pw)[tx] : float4{0.f, 0.f, 0.f, 0.f};
    float pb0 = head ? pb[0] : 0.f;
    const int op = tx >> 2, oq = tx & 3;   // output panel / offset
    float cs0 = 0.f, cs1 = 0.f, cs2 = 0.f, cs3 = 0.f;
    int ntiles = (nrows + 31) / 32;

    for (int tile = blockIdx.x; tile < ntiles; tile += gridDim.x) {
        int row0 = tile * 32;
        __syncthreads();
        {
            int gr = row0 + ldrow;
            float va[16];
            if (gr < nrows) {
                const float4* ap = reinterpret_cast<const float4*>(&in[(size_t)ldc * PANEL + (size_t)gr * 16]);
#pragma unroll
                for (int qq = 0; qq < 4; qq++) {
                    float4 v = ap[qq];
                    va[qq * 4 + 0] = v.x; va[qq * 4 + 1] = v.y;
                    va[qq * 4 + 2] = v.z; va[qq * 4 + 3] = v.w;
                }
            } else {
#pragma unroll
                for (int qq = 0; qq < 16; qq++) va[qq] = 0.f;
            }
            int kb = ldc * 16;
#pragma unroll
            for (int j = 0; j < 16; j++) at[(kb + j) * 32 + ldrow] = va[j];
        }
        __syncthreads();

        float acc[4][4];
#pragma unroll
        for (int j = 0; j < 4; j++)
#pragma unroll
            for (int c = 0; c < 4; c++) acc[j][c] = 0.f;

#pragma unroll 8
        for (int k = 0; k < D; k++) {
            float4 a = *reinterpret_cast<const float4*>(&at[k * 32 + ty * 4]);
            float4 w = *reinterpret_cast<const float4*>(&wl[k * D + tx * 4]);
            acc[0][0] += a.x * w.x; acc[0][1] += a.x * w.y; acc[0][2] += a.x * w.z; acc[0][3] += a.x * w.w;
            acc[1][0] += a.y * w.x; acc[1][1] += a.y * w.y; acc[1][2] += a.y * w.z; acc[1][3] += a.y * w.w;
            acc[2][0] += a.z * w.x; acc[2][1] += a.z * w.y; acc[2][2] += a.z * w.z; acc[2][3] += a.z * w.w;
            acc[3][0] += a.w * w.x; acc[3][1] += a.w * w.y; acc[3][2] += a.w * w.z; acc[3][3] += a.w * w.w;
        }

#pragma unroll
        for (int j = 0; j < 4; j++) {
            int gr = row0 + ty * 4 + j;
            if (gr < nrows) {
                float4 o;
                o.x = acc[j][0] + bv.x; o.y = acc[j][1] + bv.y;
                o.z = acc[j][2] + bv.z; o.w = acc[j][3] + bv.w;
                if (relu) {
                    o.x = fmaxf(o.x, 0.f); o.y = fmaxf(o.y, 0.f);
                    o.z = fmaxf(o.z, 0.f); o.w = fmaxf(o.w, 0.f);
                }
                if (head) {
                    cs0 += o.x; cs1 += o.y; cs2 += o.z; cs3 += o.w;
                    float pr = o.x * pwv.x + o.y * pwv.y + o.z * pwv.z + o.w * pwv.w;
#pragma unroll
                    for (int off = 16; off > 0; off >>= 1) pr += __shfl_xor(pr, off, 32);
                    if (tx == 0) pi_out[gr] = pr + pb0;
                } else {
                    if (dscale) {
                        float w = dscale[gr];
                        o.x *= w; o.y *= w; o.z *= w; o.w *= w;
                    }
                    *reinterpret_cast<float4*>(&out[(size_t)op * PANEL + (size_t)gr * 16 + oq * 4]) = o;
                }
            }
        }
    }

    if (head) {
        __syncthreads();
        float* csl = at;
        if (t < D) csl[t] = 0.f;
        __syncthreads();
        atomicAdd(&csl[tx * 4 + 0], cs0);
        atomicAdd(&csl[tx * 4 + 1], cs1);
        atomicAdd(&csl[tx * 4 + 2], cs2);
        atomicAdd(&csl[tx * 4 + 3], cs3);
        __syncthreads();
        if (t < D) atomicAdd(&colsum[t], csl[t]);
    }
}

// ---------------- value head ----------------

__global__ __launch_bounds__(128) void k_value(const float* __restrict__ colsum, const float* __restrict__ vw,
                                               const float* __restrict__ vb, float* __restrict__ out) {
    __shared__ float red[128];
    int t = threadIdx.x;
    red[t] = (colsum[t] * (1.0f / (float)N_NODES)) * vw[t];
    __syncthreads();
    for (int s = 64; s > 0; s >>= 1) {
        if (t < s) red[t] += red[t + s];
        __syncthreads();
    }
    if (t == 0) out[0] = red[0] + vb[0];
}

__global__ __launch_bounds__(64) void k_ws_too_small(float* __restrict__ out, int n) {
    int i = blockIdx.x * 64 + threadIdx.x;
    if (i < n) out[i] = -1e30f;
}

// ---------------- launch ----------------

extern "C" void kernel_launch(void* const* d_in, const int* in_sizes, int n_in,
                              void* d_out, int out_size, void* d_ws, size_t ws_size,
                              hipStream_t stream) {
    const float* features = (const float*)d_in[0];
    const int*   src      = (const int*)d_in[1];
    const int*   dst      = (const int*)d_in[2];
    const float* W1 = (const float*)d_in[3];
    const float* b1 = (const float*)d_in[4];
    const float* W2 = (const float*)d_in[5];
    const float* b2 = (const float*)d_in[6];
    const float* W3 = (const float*)d_in[7];
    const float* b3 = (const float*)d_in[8];
    const float* pw = (const float*)d_in[9];
    const float* pb = (const float*)d_in[10];
    const float* vw = (const float*)d_in[11];
    const float* vb = (const float*)d_in[12];
    float* out = (float*)d_out;

    char* ws = (char*)d_ws;
    size_t off = 0;
    auto alloc = [&](size_t bytes) -> char* {
        char* p = ws + off;
        off += (bytes + 255) & ~(size_t)255;
        return p;
    };
    float* dinv     = (float*)alloc((size_t)N_NODES * 4);
    int*   rowptr   = (int*)alloc((size_t)(N_NODES + 1) * 4);
    int*   blocksum = (int*)alloc(64 * 4);
    int*   blockoff = (int*)alloc(64 * 4);
    float* colsum   = (float*)alloc(D * 4);
    int*   csrc     = (int*)alloc((size_t)N_EDGES * 4);
    float* bufA     = (float*)alloc((size_t)N_NODES * D * 4);
    float* bufB     = (float*)alloc((size_t)N_NODES * D * 4);

    // CSR-build temporaries overlay bufB (dead once agg-1 writes bufB):
    // [ghd16: 64*25000 u32 = 6.4MB][ghs16: 6.4MB][rowcnt: 200KB] = 13MB < 25.6MB.
    unsigned* ghd16 = (unsigned*)bufB;
    unsigned* ghs16 = ghd16 + (size_t)NC * NW;
    int* rowcnt     = (int*)(ghs16 + (size_t)NC * NW);

    if (off > ws_size) {
        k_ws_too_small<<<(out_size + 63) / 64, 64, 0, stream>>>(out, out_size);
        return;
    }

    hipMemsetAsync(colsum, 0, (size_t)D * 4, stream);

    // CSR build: zero global atomics, edge list streamed 2x total.
    k_hist3<<<2 * NC, 512, 0, stream>>>(src, dst, ghd16, ghs16);
    k_merge3<<<(NW + 255) / 256, 256, 0, stream>>>(ghd16, ghs16, rowcnt, dinv);

    int nblk = (N_NODES + 1023) / 1024;
    k_scan1<<<nblk, 1024, 0, stream>>>(rowcnt, rowptr, blocksum, N_NODES);
    k_scan2<<<1, 64, 0, stream>>>(blocksum, blockoff, rowptr + N_NODES, nblk);
    k_scan3<<<nblk, 1024, 0, stream>>>(rowptr, blockoff, N_NODES);
    k_fill3<<<NC, 512, 0, stream>>>(src, dst, rowptr, ghd16, csrc);

    // panelize features*dinv -> bufA (panels)
    k_panelize<<<(N_NODES * 32 + 255) / 256, 256, 0, stream>>>(features, dinv, bufA);

    int aggblocks = ((N_NODES + 63) / 64) * NSH;    // 782*8 = 6256
    // layer 1: agg(bufA)->bufB ; gemm in-place panels (+dinv scale for next layer)
    k_agg<<<aggblocks, 256, 0, stream>>>(bufA, rowptr, csrc, bufB);
    k_gemm<<<512, 256, 0, stream>>>(bufB, W1, b1, bufB, N_NODES, 1, dinv,
                                    nullptr, nullptr, nullptr, nullptr);
    // layer 2
    k_agg<<<aggblocks, 256, 0, stream>>>(bufB, rowptr, csrc, bufA);
    k_gemm<<<512, 256, 0, stream>>>(bufA, W2, b2, bufA, N_NODES, 1, dinv,
                                    nullptr, nullptr, nullptr, nullptr);
    // layer 3: head mode (PI -> out, colsum; h3 never stored)
    k_agg<<<aggblocks, 256, 0, stream>>>(bufA, rowptr, csrc, bufB);
    k_gemm<<<512, 256, 0, stream>>>(bufB, W3, b3, nullptr, N_NODES, 0, nullptr,
                                    pw, pb, out, colsum);

    k_value<<<1, 128, 0, stream>>>(colsum, vw, vb, out + N_NODES);
}

// Round 16
// 309.664 us; speedup vs baseline: 1.3253x; 1.1036x over previous
//
#include <hip/hip_runtime.h>

// GCN forward, MI355X. v16 — k_agg latency fix: rows 8-padded with sentinel
// index -> branchless 8-wide gather loop (8 float4 loads in flight, was 4
// with scalar tails); csrc in u16 (half index traffic). Panels + static
// slice=bid&7 kept (v15: FETCH = compulsory-only). Rest identical to v15.

#define N_NODES 50000
#define N_EDGES 800000
#define D 128
#define NSH 8
#define PROWS (N_NODES + 8)             // +sentinel zero row at index N_NODES
#define PANEL ((size_t)PROWS * 16)
#define NC 64
#define CSZ (N_EDGES / NC)              // 12500
#define NW (N_NODES / 2)                // 25000 packed words
#define CS_CAP (N_EDGES + 8 * N_NODES)  // padded csrc capacity

// ---------------- CSR build (no global atomics) ----------------

__global__ __launch_bounds__(512) void k_hist3(const int* __restrict__ src, const int* __restrict__ dst,
                                               unsigned* __restrict__ ghd16, unsigned* __restrict__ ghs16) {
    __shared__ unsigned h[NW];          // 100 KB
    const int arr = blockIdx.x & 1;
    const int c   = blockIdx.x >> 1;
    const int t = threadIdx.x;
    for (int i = t; i < NW; i += 512) h[i] = 0u;
    __syncthreads();
    const int* __restrict__ col = arr ? src : dst;
    const int e0 = c * CSZ, e1 = e0 + CSZ;
    for (int e = e0 + t; e < e1; e += 512) {
        int n = col[e];
        atomicAdd(&h[n >> 1], 1u << ((n & 1) << 4));
    }
    __syncthreads();
    unsigned* __restrict__ outp = (arr ? ghs16 : ghd16) + (size_t)c * NW;
    for (int i = t; i < NW; i += 512) outp[i] = h[i];
}

// merge: dst partials -> exclusive chunk prefix (packed, in place) + true and
// 8-rounded row counts; src partials -> dinv.
__global__ __launch_bounds__(256) void k_merge3(unsigned* __restrict__ ghd16, const unsigned* __restrict__ ghs16,
                                                int* __restrict__ rowcnt, int* __restrict__ rowtrue,
                                                float* __restrict__ dinv) {
    int w = blockIdx.x * 256 + threadIdx.x;
    if (w >= NW) return;
    unsigned runlo = 0, runhi = 0;
#pragma unroll
    for (int c = 0; c < NC; c++) {
        unsigned v = ghd16[(size_t)c * NW + w];
        ghd16[(size_t)c * NW + w] = runlo | (runhi << 16);
        runlo += v & 0xffffu; runhi += v >> 16;
    }
    rowtrue[2 * w]     = (int)runlo;
    rowtrue[2 * w + 1] = (int)runhi;
    rowcnt[2 * w]      = (int)((runlo + 7u) & ~7u);
    rowcnt[2 * w + 1]  = (int)((runhi + 7u) & ~7u);
    unsigned dlo = 0, dhi = 0;
#pragma unroll
    for (int c = 0; c < NC; c++) {
        unsigned v = ghs16[(size_t)c * NW + w];
        dlo += v & 0xffffu; dhi += v >> 16;
    }
    dinv[2 * w]     = 1.0f / (float)(dlo > 1u ? dlo : 1u);
    dinv[2 * w + 1] = 1.0f / (float)(dhi > 1u ? dhi : 1u);
}

__global__ __launch_bounds__(1024) void k_scan1(const int* __restrict__ cnt, int* __restrict__ excl,
                                                int* __restrict__ blocksum, int n) {
    __shared__ int wsum[16];
    int i = blockIdx.x * 1024 + threadIdx.x;
    int v = (i < n) ? cnt[i] : 0;
    int lane = threadIdx.x & 63, wid = threadIdx.x >> 6;
    int x = v;
#pragma unroll
    for (int off = 1; off < 64; off <<= 1) {
        int y = __shfl_up(x, off, 64);
        if (lane >= off) x += y;
    }
    if (lane == 63) wsum[wid] = x;
    __syncthreads();
    if (threadIdx.x == 0) {
        int run = 0;
        for (int w = 0; w < 16; w++) { int t = wsum[w]; wsum[w] = run; run += t; }
        blocksum[blockIdx.x] = run;
    }
    __syncthreads();
    if (i < n) excl[i] = (x - v) + wsum[wid];
}

__global__ void k_scan2(const int* __restrict__ blocksum, int* __restrict__ blockoff,
                        int* __restrict__ rowptr_last, int nblk) {
    if (threadIdx.x == 0) {
        int run = 0;
        for (int b = 0; b < nblk; b++) { int t = blocksum[b]; blockoff[b] = run; run += t; }
        rowptr_last[0] = run;
    }
}

__global__ __launch_bounds__(1024) void k_scan3(int* __restrict__ excl, const int* __restrict__ blockoff, int n) {
    int i = blockIdx.x * 1024 + threadIdx.x;
    if (i < n) excl[i] += blockoff[blockIdx.x];
}

// fill: packed LDS counters give within-(chunk,node) pos; u16 store.
__global__ __launch_bounds__(512) void k_fill3(const int* __restrict__ src, const int* __restrict__ dst,
                                               const int* __restrict__ rowptr, const unsigned* __restrict__ ghd16,
                                               unsigned short* __restrict__ cs16) {
    __shared__ unsigned cnt[NW];        // 100 KB
    const int c = blockIdx.x;
    const int t = threadIdx.x;
    for (int i = t; i < NW; i += 512) cnt[i] = 0u;
    __syncthreads();
    const unsigned* __restrict__ basep = ghd16 + (size_t)c * NW;
    const int e0 = c * CSZ, e1 = e0 + CSZ;
    for (int e = e0 + t; e < e1; e += 512) {
        int d = dst[e];
        int sh = (d & 1) << 4;
        unsigned old = atomicAdd(&cnt[d >> 1], 1u << sh);
        int p = (int)((old >> sh) & 0xffffu);
        int base = (int)((basep[d >> 1] >> sh) & 0xffffu);
        cs16[rowptr[d] + base + p] = (unsigned short)src[e];
    }
}

// pad tails with sentinel + zero the sentinel panel rows in both buffers.
__global__ __launch_bounds__(256) void k_pad(const int* __restrict__ rowptr, const int* __restrict__ rowtrue,
                                             unsigned short* __restrict__ cs16,
                                             float* __restrict__ bufA, float* __restrict__ bufB) {
    int n = blockIdx.x * 256 + threadIdx.x;
    if (n < N_NODES) {
        int e0 = rowptr[n] + rowtrue[n], e1 = rowptr[n + 1];
        for (int e = e0; e < e1; e++) cs16[e] = (unsigned short)N_NODES;
    }
    if (blockIdx.x == 0) {
        int t = threadIdx.x;            // 256 = 2 bufs x 8 panels x 16 cols
        float* b = (t & 128) ? bufB : bufA;
        int p = (t >> 4) & 7, cc = t & 15;
        b[(size_t)p * PANEL + (size_t)N_NODES * 16 + cc] = 0.f;
    }
}

// ---------------- panelize: outp[p][node][16] = features[node][p*16..] * dinv[node] ----------------

__global__ __launch_bounds__(256) void k_panelize(const float* __restrict__ in, const float* __restrict__ dinv,
                                                  float* __restrict__ outp) {
    int tid = blockIdx.x * 256 + threadIdx.x;          // N_NODES*32 threads
    if (tid >= N_NODES * 32) return;
    int p = tid / (N_NODES * 4);
    int r = tid - p * (N_NODES * 4);
    int node = r >> 2, qq = r & 3;
    float w = dinv[node];
    float4 v = *reinterpret_cast<const float4*>(&in[(size_t)node * D + p * 16 + qq * 4]);
    v.x *= w; v.y *= w; v.z *= w; v.w *= w;
    *reinterpret_cast<float4*>(&outp[(size_t)p * PANEL + (size_t)node * 16 + qq * 4]) = v;
}

// ---------------- SpMM aggregation: panels, XCD slices, branchless 8-wide ----------------
// Rows 8-padded (sentinel -> zero row). Per step: 1 int4 (8 u16 idx) + 8
// independent float4 gathers in flight; no prologue/tail, no cross-lane ops.

__global__ __launch_bounds__(256) void k_agg(const float* __restrict__ hp,
                                             const int* __restrict__ rp, const unsigned short* __restrict__ cs16,
                                             float* __restrict__ outp) {
    const int l4 = threadIdx.x & 3;
    const int grp = threadIdx.x >> 2;               // 0..63
    const int slice = blockIdx.x & (NSH - 1);
    const int node = (blockIdx.x >> 3) * 64 + grp;
    if (node >= N_NODES) return;
    const float* __restrict__ pan = hp + (size_t)slice * PANEL + l4 * 4;
    int s0 = rp[node], s1 = rp[node + 1];           // multiples of 8
    float4 acc = {0.f, 0.f, 0.f, 0.f};
    for (int e = s0; e < s1; e += 8) {
        int4 r = *reinterpret_cast<const int4*>(&cs16[e]);   // 8 u16 indices
        int i0 = r.x & 0xffff, i1 = (r.x >> 16) & 0xffff;
        int i2 = r.y & 0xffff, i3 = (r.y >> 16) & 0xffff;
        int i4 = r.z & 0xffff, i5 = (r.z >> 16) & 0xffff;
        int i6 = r.w & 0xffff, i7 = (r.w >> 16) & 0xffff;
        float4 a0 = *reinterpret_cast<const float4*>(&pan[(size_t)i0 * 16]);
        float4 a1 = *reinterpret_cast<const float4*>(&pan[(size_t)i1 * 16]);
        float4 a2 = *reinterpret_cast<const float4*>(&pan[(size_t)i2 * 16]);
        float4 a3 = *reinterpret_cast<const float4*>(&pan[(size_t)i3 * 16]);
        float4 a4 = *reinterpret_cast<const float4*>(&pan[(size_t)i4 * 16]);
        float4 a5 = *reinterpret_cast<const float4*>(&pan[(size_t)i5 * 16]);
        float4 a6 = *reinterpret_cast<const float4*>(&pan[(size_t)i6 * 16]);
        float4 a7 = *reinterpret_cast<const float4*>(&pan[(size_t)i7 * 16]);
        acc.x += ((a0.x + a1.x) + (a2.x + a3.x)) + ((a4.x + a5.x) + (a6.x + a7.x));
        acc.y += ((a0.y + a1.y) + (a2.y + a3.y)) + ((a4.y + a5.y) + (a6.y + a7.y));
        acc.z += ((a0.z + a1.z) + (a2.z + a3.z)) + ((a4.z + a5.z) + (a6.z + a7.z));
        acc.w += ((a0.w + a1.w) + (a2.w + a3.w)) + ((a4.w + a5.w) + (a6.w + a7.w));
    }
    *reinterpret_cast<float4*>(&outp[(size_t)slice * PANEL + (size_t)node * 16 + l4 * 4]) = acc;
}

// ---------------- dense layer, panel I/O (+ fused epilogues) ----------------

__global__ __launch_bounds__(256) void k_gemm(const float* __restrict__ in, const float* __restrict__ W,
                                              const float* __restrict__ bias, float* __restrict__ out,
                                              int nrows, int relu,
                                              const float* __restrict__ dscale,
                                              const float* __restrict__ pw, const float* __restrict__ pb,
                                              float* __restrict__ pi_out, float* __restrict__ colsum) {
    __shared__ float wl[D * D];      // 64 KB
    __shared__ float at[D * 32];     // 16 KB (80 KB total: 2 blocks/CU)
    int t = threadIdx.x;
    const int head = (pw != nullptr);
    for (int i = t; i < D * D / 4; i += 256)
        reinterpret_cast<float4*>(wl)[i] = reinterpret_cast<const float4*>(W)[i];
    const int tx = t & 31;
    const int ty = t >> 5;
    const int ldrow = t & 31;
    const int ldc   = t >> 5;        // = panel index for staging
    float4 bv = reinterpret_cast<const float4*>(bias)[tx];
    float4 pwv = head ? reinterpret_cast<const float4*>(pw)[tx] : float4{0.f, 0.f, 0.f, 0.f};
    float pb0 = head ? pb[0] : 0.f;
    const int op = tx >> 2, oq = tx & 3;   // output panel / offset
    float cs0 = 0.f, cs1 = 0.f, cs2 = 0.f, cs3 = 0.f;
    int ntiles = (nrows + 31) / 32;

    for (int tile = blockIdx.x; tile < ntiles; tile += gridDim.x) {
        int row0 = tile * 32;
        __syncthreads();
        {
            int gr = row0 + ldrow;
            float va[16];
            if (gr < nrows) {
                const float4* ap = reinterpret_cast<const float4*>(&in[(size_t)ldc * PANEL + (size_t)gr * 16]);
#pragma unroll
                for (int qq = 0; qq < 4; qq++) {
                    float4 v = ap[qq];
                    va[qq * 4 + 0] = v.x; va[qq * 4 + 1] = v.y;
                    va[qq * 4 + 2] = v.z; va[qq * 4 + 3] = v.w;
                }
            } else {
#pragma unroll
                for (int qq = 0; qq < 16; qq++) va[qq] = 0.f;
            }
            int kb = ldc * 16;
#pragma unroll
            for (int j = 0; j < 16; j++) at[(kb + j) * 32 + ldrow] = va[j];
        }
        __syncthreads();

        float acc[4][4];
#pragma unroll
        for (int j = 0; j < 4; j++)
#pragma unroll
            for (int c = 0; c < 4; c++) acc[j][c] = 0.f;

#pragma unroll 8
        for (int k = 0; k < D; k++) {
            float4 a = *reinterpret_cast<const float4*>(&at[k * 32 + ty * 4]);
            float4 w = *reinterpret_cast<const float4*>(&wl[k * D + tx * 4]);
            acc[0][0] += a.x * w.x; acc[0][1] += a.x * w.y; acc[0][2] += a.x * w.z; acc[0][3] += a.x * w.w;
            acc[1][0] += a.y * w.x; acc[1][1] += a.y * w.y; acc[1][2] += a.y * w.z; acc[1][3] += a.y * w.w;
            acc[2][0] += a.z * w.x; acc[2][1] += a.z * w.y; acc[2][2] += a.z * w.z; acc[2][3] += a.z * w.w;
            acc[3][0] += a.w * w.x; acc[3][1] += a.w * w.y; acc[3][2] += a.w * w.z; acc[3][3] += a.w * w.w;
        }

#pragma unroll
        for (int j = 0; j < 4; j++) {
            int gr = row0 + ty * 4 + j;
            if (gr < nrows) {
                float4 o;
                o.x = acc[j][0] + bv.x; o.y = acc[j][1] + bv.y;
                o.z = acc[j][2] + bv.z; o.w = acc[j][3] + bv.w;
                if (relu) {
                    o.x = fmaxf(o.x, 0.f); o.y = fmaxf(o.y, 0.f);
                    o.z = fmaxf(o.z, 0.f); o.w = fmaxf(o.w, 0.f);
                }
                if (head) {
                    cs0 += o.x; cs1 += o.y; cs2 += o.z; cs3 += o.w;
                    float pr = o.x * pwv.x + o.y * pwv.y + o.z * pwv.z + o.w * pwv.w;
#pragma unroll
                    for (int off = 16; off > 0; off >>= 1) pr += __shfl_xor(pr, off, 32);
                    if (tx == 0) pi_out[gr] = pr + pb0;
                } else {
                    if (dscale) {
                        float w = dscale[gr];
                        o.x *= w; o.y *= w; o.z *= w; o.w *= w;
                    }
                    *reinterpret_cast<float4*>(&out[(size_t)op * PANEL + (size_t)gr * 16 + oq * 4]) = o;
                }
            }
        }
    }

    if (head) {
        __syncthreads();
        float* csl = at;
        if (t < D) csl[t] = 0.f;
        __syncthreads();
        atomicAdd(&csl[tx * 4 + 0], cs0);
        atomicAdd(&csl[tx * 4 + 1], cs1);
        atomicAdd(&csl[tx * 4 + 2], cs2);
        atomicAdd(&csl[tx * 4 + 3], cs3);
        __syncthreads();
        if (t < D) atomicAdd(&colsum[t], csl[t]);
    }
}

// ---------------- value head ----------------

__global__ __launch_bounds__(128) void k_value(const float* __restrict__ colsum, const float* __restrict__ vw,
                                               const float* __restrict__ vb, float* __restrict__ out) {
    __shared__ float red[128];
    int t = threadIdx.x;
    red[t] = (colsum[t] * (1.0f / (float)N_NODES)) * vw[t];
    __syncthreads();
    for (int s = 64; s > 0; s >>= 1) {
        if (t < s) red[t] += red[t + s];
        __syncthreads();
    }
    if (t == 0) out[0] = red[0] + vb[0];
}

__global__ __launch_bounds__(64) void k_ws_too_small(float* __restrict__ out, int n) {
    int i = blockIdx.x * 64 + threadIdx.x;
    if (i < n) out[i] = -1e30f;
}

// ---------------- launch ----------------

extern "C" void kernel_launch(void* const* d_in, const int* in_sizes, int n_in,
                              void* d_out, int out_size, void* d_ws, size_t ws_size,
                              hipStream_t stream) {
    const float* features = (const float*)d_in[0];
    const int*   src      = (const int*)d_in[1];
    const int*   dst      = (const int*)d_in[2];
    const float* W1 = (const float*)d_in[3];
    const float* b1 = (const float*)d_in[4];
    const float* W2 = (const float*)d_in[5];
    const float* b2 = (const float*)d_in[6];
    const float* W3 = (const float*)d_in[7];
    const float* b3 = (const float*)d_in[8];
    const float* pw = (const float*)d_in[9];
    const float* pb = (const float*)d_in[10];
    const float* vw = (const float*)d_in[11];
    const float* vb = (const float*)d_in[12];
    float* out = (float*)d_out;

    char* ws = (char*)d_ws;
    size_t off = 0;
    auto alloc = [&](size_t bytes) -> char* {
        char* p = ws + off;
        off += (bytes + 255) & ~(size_t)255;
        return p;
    };
    float* dinv     = (float*)alloc((size_t)N_NODES * 4);
    int*   rowptr   = (int*)alloc((size_t)(N_NODES + 1) * 4);
    int*   rowcnt   = (int*)alloc((size_t)N_NODES * 4);
    int*   rowtrue  = (int*)alloc((size_t)N_NODES * 4);
    int*   blocksum = (int*)alloc(64 * 4);
    int*   blockoff = (int*)alloc(64 * 4);
    float* colsum   = (float*)alloc(D * 4);
    unsigned short* cs16 = (unsigned short*)alloc((size_t)CS_CAP * 2);
    float* bufA     = (float*)alloc((size_t)NSH * PANEL * 4);
    float* bufB     = (float*)alloc((size_t)NSH * PANEL * 4);

    // CSR-build temporaries overlay bufB (dead after k_fill3):
    // [ghd16: 6.4MB][ghs16: 6.4MB] = 12.8MB < 25.6MB.
    unsigned* ghd16 = (unsigned*)bufB;
    unsigned* ghs16 = ghd16 + (size_t)NC * NW;

    if (off > ws_size) {
        k_ws_too_small<<<(out_size + 63) / 64, 64, 0, stream>>>(out, out_size);
        return;
    }

    hipMemsetAsync(colsum, 0, (size_t)D * 4, stream);

    // CSR build: zero global atomics, edge list streamed 2x total.
    k_hist3<<<2 * NC, 512, 0, stream>>>(src, dst, ghd16, ghs16);
    k_merge3<<<(NW + 255) / 256, 256, 0, stream>>>(ghd16, ghs16, rowcnt, rowtrue, dinv);

    int nblk = (N_NODES + 1023) / 1024;
    k_scan1<<<nblk, 1024, 0, stream>>>(rowcnt, rowptr, blocksum, N_NODES);
    k_scan2<<<1, 64, 0, stream>>>(blocksum, blockoff, rowptr + N_NODES, nblk);
    k_scan3<<<nblk, 1024, 0, stream>>>(rowptr, blockoff, N_NODES);
    k_fill3<<<NC, 512, 0, stream>>>(src, dst, rowptr, ghd16, cs16);
    k_pad<<<(N_NODES + 255) / 256, 256, 0, stream>>>(rowptr, rowtrue, cs16, bufA, bufB);

    // panelize features*dinv -> bufA (panels)
    k_panelize<<<(N_NODES * 32 + 255) / 256, 256, 0, stream>>>(features, dinv, bufA);

    int aggblocks = ((N_NODES + 63) / 64) * NSH;    // 782*8 = 6256
    // layer 1: agg(bufA)->bufB ; gemm in-place panels (+dinv scale for next layer)
    k_agg<<<aggblocks, 256, 0, stream>>>(bufA, rowptr, cs16, bufB);
    k_gemm<<<512, 256, 0, stream>>>(bufB, W1, b1, bufB, N_NODES, 1, dinv,
                                    nullptr, nullptr, nullptr, nullptr);
    // layer 2
    k_agg<<<aggblocks, 256, 0, stream>>>(bufB, rowptr, cs16, bufA);
    k_gemm<<<512, 256, 0, stream>>>(bufA, W2, b2, bufA, N_NODES, 1, dinv,
                                    nullptr, nullptr, nullptr, nullptr);
    // layer 3: head mode (PI -> out, colsum; h3 never stored)
    k_agg<<<aggblocks, 256, 0, stream>>>(bufA, rowptr, cs16, bufB);
    k_gemm<<<512, 256, 0, stream>>>(bufB, W3, b3, nullptr, N_NODES, 0, nullptr,
                                    pw, pb, out, colsum);

    k_value<<<1, 128, 0, stream>>>(colsum, vw, vb, out + N_NODES);
}